// Round 3
// baseline (1022.789 us; speedup 1.0000x reference)
//
#include <hip/hip_runtime.h>
#include <hip/hip_bf16.h>
#include <stdint.h>

typedef float  f32x4 __attribute__((ext_vector_type(4)));
typedef short  s16x8 __attribute__((ext_vector_type(8)));

#define GLOAD_LDS16(g, l)                                                          \
  __builtin_amdgcn_global_load_lds(                                               \
      (const __attribute__((address_space(1))) unsigned int*)(g),                 \
      (__attribute__((address_space(3))) unsigned int*)(l), 16, 0, 0)

#define WAITVM_(N) asm volatile("s_waitcnt vmcnt(" #N ")" ::: "memory")
#define WAITVM(N) WAITVM_(N)

static __device__ __forceinline__ unsigned short f2bf(float f) {
  union { __hip_bfloat16 b; unsigned short s; } cv;
  cv.b = __float2bfloat16(f);          // RNE; compiler pairs into v_cvt_pk_bf16_f32
  return cv.s;
}

static __device__ __forceinline__ int swz_e(int r) { return ((r & 3) ^ ((r >> 2) & 1)); }
static __device__ __forceinline__ int swz_byte(int r, int c) {
  return r * 64 + (((c ^ swz_e(r)) & 3) << 4);
}

// ---------------- pre-pass: Wt[k-1][col][d] = bf16(W[k][d][col]), k = 1..8 ----------------
__global__ __launch_bounds__(256) void transpose_w(const float* __restrict__ w,
                                                   short* __restrict__ wt) {
  __shared__ unsigned int lds[64 * 33];
  const int t = threadIdx.x;
  const int bid = blockIdx.x;
  const int kb = bid >> 8;            // 0..7  (k = kb+1)
  const int db = (bid >> 4) & 15;
  const int cb = bid & 15;
  const int d0 = db * 64, c0 = cb * 64;
  const float* src = w + (size_t)(kb + 1) * 1048576 + (size_t)d0 * 1024 + c0;
  #pragma unroll
  for (int p = 0; p < 4; ++p) {
    int dl = p * 16 + (t >> 4);
    int c4 = (t & 15) * 4;
    f32x4 f = *(const f32x4*)(src + (size_t)dl * 1024 + c4);
    unsigned lo = (unsigned)f2bf(f.x) | ((unsigned)f2bf(f.y) << 16);
    unsigned hi = (unsigned)f2bf(f.z) | ((unsigned)f2bf(f.w) << 16);
    lds[dl * 33 + (t & 15) * 2]     = lo;
    lds[dl * 33 + (t & 15) * 2 + 1] = hi;
  }
  __syncthreads();
  const int col = t >> 2;   // 0..63
  const int dc  = t & 3;    // 16-d chunk
  union { unsigned short u[8]; s16x8 v; } o0, o1;
  #pragma unroll
  for (int j = 0; j < 16; ++j) {
    int dl = dc * 16 + j;
    unsigned word = lds[dl * 33 + (col >> 1)];
    unsigned short e = (col & 1) ? (unsigned short)(word >> 16) : (unsigned short)(word & 0xffffu);
    if (j < 8) o0.u[j] = e; else o1.u[j - 8] = e;
  }
  short* dst = wt + ((size_t)(kb * 1024 + c0 + col) * 1024 + d0 + dc * 16);
  *(s16x8*)dst       = o0.v;
  *(s16x8*)(dst + 8) = o1.v;
}

// ---------------- bias[c] = sum_d W[0][d][c] ----------------
__global__ __launch_bounds__(256) void bias_k(const float* __restrict__ w,
                                              float* __restrict__ b) {
  __shared__ float red[256];
  const int t = threadIdx.x;
  const int col = blockIdx.x * 64 + (t & 63);
  const int seg = t >> 6;
  float s = 0.f;
  const float* p = w + (size_t)(seg * 256) * 1024 + col;
  for (int d = 0; d < 256; ++d) s += p[(size_t)d * 1024];
  red[t] = s;
  __syncthreads();
  if (t < 64) b[col] = red[t] + red[t + 64] + red[t + 128] + red[t + 192];
}

// ---------------- out init: out[r][c] = bias[c] (or 0) ----------------
__global__ __launch_bounds__(256) void init_out(const float* __restrict__ bias,
                                                float* __restrict__ out, int has_bias) {
  const size_t i = (size_t)blockIdx.x * 256 + threadIdx.x;
  const int c = (int)((i * 4) & 1023);
  f32x4 v = has_bias ? *(const f32x4*)(bias + c) : (f32x4){0.f, 0.f, 0.f, 0.f};
  *(f32x4*)(out + i * 4) = v;
}

// ---------------- fused Chebyshev GEMM ----------------
// block 128M x 256N, split-K x2, 4 waves (2x2), wave 64x128.
// A generated IN REGISTERS (each lane computes exactly its MFMA fragment rows/dims).
// B: 4-deep LDS pipeline via global_load_lds, counted vmcnt(8), 1 raw s_barrier/step.
template <bool USE_WS>
__global__ __launch_bounds__(256, 2) void cheb_gemm(
    const float* __restrict__ x, const float* __restrict__ w,
    const short* __restrict__ wt, float* __restrict__ out) {
  constexpr int KP = USE_WS ? 8 : 9;
  constexpr int NSTEP = 16 * KP;
  __shared__ short Bsm[USE_WS ? 32768 : 8192];   // 4 bufs x 16KB | 1 buf 16KB

  const int tid = threadIdx.x, lane = tid & 63, wid = tid >> 6;
  const int bid = blockIdx.x;
  const int swz = (bid & 7) * 64 + (bid >> 3);   // XCD swizzle, 512%8==0 bijective
  const int kb = swz & 1;
  const int t2 = swz >> 1;
  const int mb = t2 & 63, nb = t2 >> 6;
  const int rowbase = mb * 128, colbase = nb * 256;
  const int kbase = kb * 512;
  const int wr = wid >> 1, wc = wid & 1;
  const int la = lane & 15, lg = lane >> 4;

  f32x4 acc[4][8];
  #pragma unroll
  for (int m = 0; m < 4; ++m)
    #pragma unroll
    for (int n = 0; n < 8; ++n) acc[m][n] = (f32x4){0.f, 0.f, 0.f, 0.f};

  // B-frag read base: col = wc*128 + n*16 + la, chunk lg; swz_e(col) == swz_e(la)
  const int e_la = (la & 3) ^ ((la >> 2) & 1);
  const int bbase = (wc * 128 + la) * 64 + ((lg ^ e_la) << 4);

  // recurrence state: rows wr*64+m*16+la (m=0..3), dims strip*32 + lg*8 .. +8
  float p1[4][8], p2[4][8];
  unsigned x2h[4][4];                 // 2x packed as f16x2
  const int xoff = (rowbase + wr * 64 + la) * 1024 + kbase + lg * 8;

  if constexpr (USE_WS) {
    // gload src: col_j = wid*64 + j*16 + (lane>>2); e(col) indep of j
    const int ge   = ((lane >> 2) & 3) ^ ((lane >> 4) & 1);
    const int goff = ((lane & 3) ^ ge) * 8;
    const short* bsrc = wt + (size_t)(colbase + wid * 64 + (lane >> 2)) * 1024 + kbase + goff;

#define ISSUE(T, BUF)                                                            \
    { const int k_i = (T) & 7, st_i = (T) >> 3;                                  \
      const short* g0 = bsrc + ((size_t)k_i << 20) + st_i * 32;                  \
      _Pragma("unroll")                                                          \
      for (int j_ = 0; j_ < 4; ++j_)                                             \
        GLOAD_LDS16(g0 + j_ * 16384,                                             \
                    (char*)Bsm + (BUF) * 16384 + (wid * 4 + j_) * 1024); }

#define STEPW(S, BUF, VM)                                                        \
    { WAITVM(VM);                                                                \
      __builtin_amdgcn_s_barrier();                                              \
      const int r_ = (S) & 7, st_ = (S) >> 3;                                    \
      f32x4 xa_[4], xb_[4];                                                      \
      if (r_ == 0) {                                                             \
        _Pragma("unroll")                                                        \
        for (int m_ = 0; m_ < 4; ++m_) {                                         \
          const float* xg = x + xoff + m_ * 16384 + st_ * 32;                    \
          xa_[m_] = *(const f32x4*)xg;  xb_[m_] = *(const f32x4*)(xg + 4);       \
        }                                                                        \
      }                                                                          \
      if ((S) + 3 < NSTEP) { ISSUE((S) + 3, ((BUF) + 3) & 3); }                  \
      if (r_ == 0) {                                                             \
        _Pragma("unroll")                                                        \
        for (int m_ = 0; m_ < 4; ++m_) {                                         \
          _Pragma("unroll")                                                      \
          for (int q_ = 0; q_ < 4; ++q_) {                                       \
            p1[m_][q_]     = xa_[m_][q_];                                        \
            p1[m_][q_ + 4] = xb_[m_][q_];                                        \
          }                                                                      \
          _Pragma("unroll")                                                      \
          for (int i_ = 0; i_ < 8; ++i_) p2[m_][i_] = 1.f;                       \
          _Pragma("unroll")                                                      \
          for (int h_ = 0; h_ < 4; ++h_) {                                       \
            union { unsigned u; _Float16 h2[2]; } t_;                            \
            t_.h2[0] = (_Float16)(p1[m_][2 * h_]     + p1[m_][2 * h_]);          \
            t_.h2[1] = (_Float16)(p1[m_][2 * h_ + 1] + p1[m_][2 * h_ + 1]);      \
            x2h[m_][h_] = t_.u;                                                  \
          }                                                                      \
        }                                                                        \
      } else {                                                                   \
        _Pragma("unroll")                                                        \
        for (int m_ = 0; m_ < 4; ++m_)                                           \
          _Pragma("unroll")                                                      \
          for (int i_ = 0; i_ < 8; ++i_) {                                       \
            union { unsigned u; _Float16 h2[2]; } t_; t_.u = x2h[m_][i_ >> 1];   \
            float x2v = (float)t_.h2[i_ & 1];                                    \
            float cur = fmaf(x2v, p1[m_][i_], -p2[m_][i_]);                      \
            p2[m_][i_] = p1[m_][i_]; p1[m_][i_] = cur;                           \
          }                                                                      \
      }                                                                          \
      union { unsigned short u[8]; s16x8 v; } af_[4];                            \
      _Pragma("unroll")                                                          \
      for (int m_ = 0; m_ < 4; ++m_)                                             \
        _Pragma("unroll")                                                        \
        for (int i_ = 0; i_ < 8; ++i_) af_[m_].u[i_] = f2bf(p1[m_][i_]);         \
      __builtin_amdgcn_s_setprio(1);                                             \
      _Pragma("unroll")                                                          \
      for (int n_ = 0; n_ < 8; ++n_) {                                           \
        s16x8 bf_ = *(const s16x8*)((char*)Bsm + (BUF) * 16384 + bbase + n_ * 1024); \
        _Pragma("unroll")                                                        \
        for (int m_ = 0; m_ < 4; ++m_)                                           \
          acc[m_][n_] = __builtin_amdgcn_mfma_f32_16x16x32_bf16(af_[m_].v, bf_, acc[m_][n_], 0, 0, 0); \
      }                                                                          \
      __builtin_amdgcn_s_setprio(0); }

    ISSUE(0, 0); ISSUE(1, 1); ISSUE(2, 2);
    #pragma unroll 1
    for (int s4 = 0; s4 < NSTEP - 4; s4 += 4) {
      STEPW(s4 + 0, 0, 8);
      STEPW(s4 + 1, 1, 8);
      STEPW(s4 + 2, 2, 8);
      STEPW(s4 + 3, 3, 8);
    }
    STEPW(NSTEP - 4, 0, 8);
    STEPW(NSTEP - 3, 1, 8);
    STEPW(NSTEP - 2, 2, 4);
    STEPW(NSTEP - 1, 3, 0);
#undef STEPW
#undef ISSUE
  } else {
    // fallback: single-buffer, f32->bf16 staging, 2 barriers/step (correctness path)
    #pragma unroll 1
    for (int s = 0; s < NSTEP; ++s) {
      const int r = s % 9, st = s / 9;
      const int d0 = kbase + st * 32;
      __syncthreads();
      { const int dd = tid & 31, cg = tid >> 5;
        const float* ws_ = w + (size_t)r * 1048576 + (size_t)(d0 + dd) * 1024 + colbase + cg * 4;
        #pragma unroll
        for (int p_ = 0; p_ < 8; ++p_) {
          f32x4 f_ = *(const f32x4*)(ws_ + p_ * 32);
          #pragma unroll
          for (int jj = 0; jj < 4; ++jj) {
            int col = cg * 4 + p_ * 32 + jj;
            int byt = col * 64 + ((dd & 7) << 1) + ((((dd >> 3) ^ swz_e(col)) & 3) << 4);
            *(unsigned short*)((char*)Bsm + byt) = f2bf(f_[jj]);
          } } }
      union { unsigned short u[8]; s16x8 v; } af_[4];
      if (r == 0) {
        #pragma unroll
        for (int m = 0; m < 4; ++m) {
          const float* xg = x + xoff + m * 16384 + st * 32;
          f32x4 a = *(const f32x4*)xg, b = *(const f32x4*)(xg + 4);
          #pragma unroll
          for (int q = 0; q < 4; ++q) { p1[m][q] = a[q]; p1[m][q + 4] = b[q]; }
          #pragma unroll
          for (int i = 0; i < 8; ++i) { p2[m][i] = 1.f; af_[m].u[i] = 0x3f80; }
          #pragma unroll
          for (int h = 0; h < 4; ++h) {
            union { unsigned u; _Float16 h2[2]; } t;
            t.h2[0] = (_Float16)(2.f * p1[m][2 * h]);
            t.h2[1] = (_Float16)(2.f * p1[m][2 * h + 1]);
            x2h[m][h] = t.u;
          }
        }
      } else if (r == 1) {
        #pragma unroll
        for (int m = 0; m < 4; ++m)
          #pragma unroll
          for (int i = 0; i < 8; ++i) af_[m].u[i] = f2bf(p1[m][i]);
      } else {
        #pragma unroll
        for (int m = 0; m < 4; ++m)
          #pragma unroll
          for (int i = 0; i < 8; ++i) {
            union { unsigned u; _Float16 h2[2]; } t; t.u = x2h[m][i >> 1];
            float cur = fmaf((float)t.h2[i & 1], p1[m][i], -p2[m][i]);
            p2[m][i] = p1[m][i]; p1[m][i] = cur;
            af_[m].u[i] = f2bf(cur);
          }
      }
      __syncthreads();
      #pragma unroll
      for (int n = 0; n < 8; ++n) {
        s16x8 bf_ = *(const s16x8*)((char*)Bsm + bbase + n * 1024);
        #pragma unroll
        for (int m = 0; m < 4; ++m)
          acc[m][n] = __builtin_amdgcn_mfma_f32_16x16x32_bf16(af_[m].v, bf_, acc[m][n], 0, 0, 0);
      }
    }
  }

  // epilogue: out += acc (split-K partial), hardware f32 atomics
  #pragma unroll
  for (int m = 0; m < 4; ++m) {
    const int r0 = rowbase + wr * 64 + m * 16 + lg * 4;
    #pragma unroll
    for (int n = 0; n < 8; ++n) {
      const int c = colbase + wc * 128 + n * 16 + la;
      #pragma unroll
      for (int j = 0; j < 4; ++j)
        unsafeAtomicAdd(&out[(size_t)(r0 + j) * 1024 + c], acc[m][n][j]);
    }
  }
}

extern "C" void kernel_launch(void* const* d_in, const int* in_sizes, int n_in,
                              void* d_out, int out_size, void* d_ws, size_t ws_size,
                              hipStream_t stream) {
  const float* x = (const float*)d_in[0];
  const float* w = (const float*)d_in[1];
  float* out = (float*)d_out;

  const size_t WT_BYTES = (size_t)8 * 1024 * 1024 * 2;   // 16 MiB
  const bool use_ws = ws_size >= WT_BYTES + 4096;

  if (use_ws) {
    short* wt   = (short*)d_ws;
    float* bias = (float*)((char*)d_ws + WT_BYTES);
    transpose_w<<<2048, 256, 0, stream>>>(w, wt);
    bias_k<<<16, 256, 0, stream>>>(w, bias);
    init_out<<<8192, 256, 0, stream>>>(bias, out, 1);
    cheb_gemm<true><<<512, 256, 0, stream>>>(x, w, wt, out);
  } else {
    init_out<<<8192, 256, 0, stream>>>(nullptr, out, 0);
    cheb_gemm<false><<<512, 256, 0, stream>>>(x, w, nullptr, out);
  }
}

// Round 4
// 401.368 us; speedup vs baseline: 2.5483x; 2.5483x over previous
//
#include <hip/hip_runtime.h>
#include <hip/hip_bf16.h>
#include <stdint.h>

typedef float  f32x4 __attribute__((ext_vector_type(4)));
typedef short  s16x8 __attribute__((ext_vector_type(8)));

#define GLOAD_LDS16(g, l)                                                          \
  __builtin_amdgcn_global_load_lds(                                               \
      (const __attribute__((address_space(1))) unsigned int*)(g),                 \
      (__attribute__((address_space(3))) unsigned int*)(l), 16, 0, 0)

#define WAITVM_(N) asm volatile("s_waitcnt vmcnt(" #N ")" ::: "memory")
#define WAITVM(N) WAITVM_(N)
#define WAITLGKM0 asm volatile("s_waitcnt lgkmcnt(0)" ::: "memory")

static __device__ __forceinline__ unsigned short f2bf(float f) {
  union { __hip_bfloat16 b; unsigned short s; } cv;
  cv.b = __float2bfloat16(f);          // RNE; compiler pairs into v_cvt_pk_bf16_f32
  return cv.s;
}

static __device__ __forceinline__ int swz_e(int r) { return ((r & 3) ^ ((r >> 2) & 1)); }
static __device__ __forceinline__ int swz_byte(int r, int c) {
  return r * 64 + (((c ^ swz_e(r)) & 3) << 4);
}

// ---------------- pre-pass: Wt[k-1][col][d] = bf16(W[k][d][col]), k = 1..8 ----------------
__global__ __launch_bounds__(256) void transpose_w(const float* __restrict__ w,
                                                   short* __restrict__ wt) {
  __shared__ unsigned int lds[64 * 33];
  const int t = threadIdx.x;
  const int bid = blockIdx.x;
  const int kb = bid >> 8;            // 0..7  (k = kb+1)
  const int db = (bid >> 4) & 15;
  const int cb = bid & 15;
  const int d0 = db * 64, c0 = cb * 64;
  const float* src = w + (size_t)(kb + 1) * 1048576 + (size_t)d0 * 1024 + c0;
  #pragma unroll
  for (int p = 0; p < 4; ++p) {
    int dl = p * 16 + (t >> 4);
    int c4 = (t & 15) * 4;
    f32x4 f = *(const f32x4*)(src + (size_t)dl * 1024 + c4);
    unsigned lo = (unsigned)f2bf(f.x) | ((unsigned)f2bf(f.y) << 16);
    unsigned hi = (unsigned)f2bf(f.z) | ((unsigned)f2bf(f.w) << 16);
    lds[dl * 33 + (t & 15) * 2]     = lo;
    lds[dl * 33 + (t & 15) * 2 + 1] = hi;
  }
  __syncthreads();
  const int col = t >> 2;   // 0..63
  const int dc  = t & 3;    // 16-d chunk
  union { unsigned short u[8]; s16x8 v; } o0, o1;
  #pragma unroll
  for (int j = 0; j < 16; ++j) {
    int dl = dc * 16 + j;
    unsigned word = lds[dl * 33 + (col >> 1)];
    unsigned short e = (col & 1) ? (unsigned short)(word >> 16) : (unsigned short)(word & 0xffffu);
    if (j < 8) o0.u[j] = e; else o1.u[j - 8] = e;
  }
  short* dst = wt + ((size_t)(kb * 1024 + c0 + col) * 1024 + d0 + dc * 16);
  *(s16x8*)dst       = o0.v;
  *(s16x8*)(dst + 8) = o1.v;
}

// ---------------- bias[c] = sum_d W[0][d][c] ----------------
__global__ __launch_bounds__(256) void bias_k(const float* __restrict__ w,
                                              float* __restrict__ b) {
  __shared__ float red[256];
  const int t = threadIdx.x;
  const int col = blockIdx.x * 64 + (t & 63);
  const int seg = t >> 6;
  float s = 0.f;
  const float* p = w + (size_t)(seg * 256) * 1024 + col;
  for (int d = 0; d < 256; ++d) s += p[(size_t)d * 1024];
  red[t] = s;
  __syncthreads();
  if (t < 64) b[col] = red[t] + red[t + 64] + red[t + 128] + red[t + 192];
}

// ---------------- out init: out[r][c] = bias[c] (or 0) ----------------
__global__ __launch_bounds__(256) void init_out(const float* __restrict__ bias,
                                                float* __restrict__ out, int has_bias) {
  const size_t i = (size_t)blockIdx.x * 256 + threadIdx.x;
  const int c = (int)((i * 4) & 1023);
  f32x4 v = has_bias ? *(const f32x4*)(bias + c) : (f32x4){0.f, 0.f, 0.f, 0.f};
  *(f32x4*)(out + i * 4) = v;
}

// ---------------- fused Chebyshev GEMM ----------------
// block 128M x 256N, split-K x2, 4 waves (2x2), wave 64x128, BK=32.
// A staged via LDS (2 buffers, cheap registers); B: 4-deep LDS pipeline via
// global_load_lds with counted vmcnt(8); ONE raw s_barrier + lgkmcnt(0) per step.
template <bool USE_WS>
__global__ __launch_bounds__(256, 2) void cheb_gemm(
    const float* __restrict__ x, const float* __restrict__ w,
    const short* __restrict__ wt, float* __restrict__ out) {
  __shared__ short Asm[2][4096];   // 2 x 8KB: [128 rows][32 dims] swizzled
  __shared__ short Bsm[4][8192];   // 4 x 16KB: [256 cols][32 dims] swizzled

  const int tid = threadIdx.x, lane = tid & 63, wid = tid >> 6;
  const int bid = blockIdx.x;
  const int swz = (bid & 7) * 64 + (bid >> 3);   // XCD swizzle, 512%8==0 bijective
  const int kb = swz & 1;
  const int t2 = swz >> 1;
  const int mb = t2 & 63, nb = t2 >> 6;
  const int rowbase = mb * 128, colbase = nb * 256;
  const int kbase = kb * 512;
  const int wr = wid >> 1, wc = wid & 1;
  const int la = lane & 15, lg = lane >> 4;

  f32x4 acc[4][8];
  #pragma unroll
  for (int m = 0; m < 4; ++m)
    #pragma unroll
    for (int n = 0; n < 8; ++n) acc[m][n] = (f32x4){0.f, 0.f, 0.f, 0.f};

  // fragment read bases (swz_e(row) == swz_e(la) since strides are mult of 8)
  const int e_la = (la & 3) ^ ((la >> 2) & 1);
  const int bbase = (wc * 128 + la) * 64 + ((lg ^ e_la) << 4);
  const int abase = (wr * 64 + la) * 64 + ((lg ^ e_la) << 4);

  // A generation: thread owns row (tid&127), dims h*16 .. h*16+16 of each strip
  const int arow = tid & 127, h = tid >> 7;
  const int aw0 = swz_byte(arow, 2 * h), aw1 = swz_byte(arow, 2 * h + 1);
  const float* xrow = x + (size_t)(rowbase + arow) * 1024 + kbase + h * 16;

  float p1[16], p2[16];
  unsigned x2h[8];                 // 2x packed f16x2 (validated numerics, round 3)
  f32x4 xq[4];                     // next-strip x prefetch

  if constexpr (USE_WS) {
    // gload source: per-lane pre-swizzled (col = wid*64 + j*16 + (lane>>2))
    const int ge   = swz_e(lane >> 2);
    const int goff = ((lane & 3) ^ ge) * 8;
    const short* bsrc = wt + (size_t)(colbase + wid * 64 + (lane >> 2)) * 1024 + kbase + goff;

#define ISSUE(T, BUF)                                                              \
  { const int k_i = (T) & 7, st_i = (T) >> 3;                                      \
    const short* g0_ = bsrc + ((size_t)k_i << 20) + st_i * 32;                     \
    char* l0_ = (char*)&Bsm[BUF][0] + wid * 4096;                                  \
    _Pragma("unroll")                                                              \
    for (int j_ = 0; j_ < 4; ++j_)                                                 \
      GLOAD_LDS16(g0_ + j_ * 16384, l0_ + j_ * 1024); }

#define GENW(S)                                                                    \
  { const int S_ = (S);                                                            \
    const int r_ = S_ & 7;                                                         \
    union { unsigned short u[8]; s16x8 v; } o0_, o1_;                              \
    if (r_ == 0) {                                                                 \
      const int st_ = S_ >> 3;                                                     \
      _Pragma("unroll")                                                            \
      for (int i_ = 0; i_ < 16; ++i_) { p1[i_] = xq[i_ >> 2][i_ & 3]; p2[i_] = 1.f; } \
      _Pragma("unroll")                                                            \
      for (int i_ = 0; i_ < 8; ++i_) {                                             \
        union { unsigned u; _Float16 f[2]; } t_;                                   \
        t_.f[0] = (_Float16)(p1[2 * i_]     + p1[2 * i_]);                         \
        t_.f[1] = (_Float16)(p1[2 * i_ + 1] + p1[2 * i_ + 1]);                     \
        x2h[i_] = t_.u;                                                            \
      }                                                                            \
      if (st_ + 1 < 16) {                                                          \
        _Pragma("unroll")                                                          \
        for (int q_ = 0; q_ < 4; ++q_)                                             \
          xq[q_] = *(const f32x4*)(xrow + (st_ + 1) * 32 + q_ * 4);                \
      }                                                                            \
      _Pragma("unroll")                                                            \
      for (int i_ = 0; i_ < 8; ++i_) { o0_.u[i_] = f2bf(p1[i_]); o1_.u[i_] = f2bf(p1[i_ + 8]); } \
    } else {                                                                       \
      _Pragma("unroll")                                                            \
      for (int i_ = 0; i_ < 16; ++i_) {                                            \
        union { unsigned u; _Float16 f[2]; } t_; t_.u = x2h[i_ >> 1];              \
        float cur_ = fmaf((float)t_.f[i_ & 1], p1[i_], -p2[i_]);                   \
        p2[i_] = p1[i_]; p1[i_] = cur_;                                            \
        unsigned short e_ = f2bf(cur_);                                            \
        if (i_ < 8) o0_.u[i_] = e_; else o1_.u[i_ - 8] = e_;                       \
      }                                                                            \
    }                                                                              \
    *(s16x8*)((char*)&Asm[S_ & 1][0] + aw0) = o0_.v;                               \
    *(s16x8*)((char*)&Asm[S_ & 1][0] + aw1) = o1_.v; }

#define STEP(S, BUF, VM)                                                           \
  { WAITLGKM0;                                                                     \
    WAITVM(VM);                                                                    \
    __builtin_amdgcn_s_barrier();                                                  \
    if ((S) + 3 < 128) { ISSUE((S) + 3, ((BUF) + 3) & 3); }                        \
    if ((S) + 1 < 128) { GENW((S) + 1); }                                          \
    s16x8 af_[4];                                                                  \
    _Pragma("unroll")                                                              \
    for (int m_ = 0; m_ < 4; ++m_)                                                 \
      af_[m_] = *(const s16x8*)((char*)&Asm[(S) & 1][0] + abase + m_ * 1024);      \
    __builtin_amdgcn_s_setprio(1);                                                 \
    _Pragma("unroll")                                                              \
    for (int n_ = 0; n_ < 8; ++n_) {                                               \
      s16x8 bf_ = *(const s16x8*)((char*)&Bsm[BUF][0] + bbase + n_ * 1024);        \
      _Pragma("unroll")                                                            \
      for (int m_ = 0; m_ < 4; ++m_)                                               \
        acc[m_][n_] = __builtin_amdgcn_mfma_f32_16x16x32_bf16(af_[m_], bf_, acc[m_][n_], 0, 0, 0); \
    }                                                                              \
    __builtin_amdgcn_s_setprio(0); }

    // prologue: x (oldest in vmem queue) then 3 B-tiles; A[0] into Asm[0]
    #pragma unroll
    for (int q = 0; q < 4; ++q) xq[q] = *(const f32x4*)(xrow + q * 4);
    ISSUE(0, 0); ISSUE(1, 1); ISSUE(2, 2);
    GENW(0);

    #pragma unroll 1
    for (int s4 = 0; s4 < 124; s4 += 4) {
      STEP(s4 + 0, 0, 8);
      STEP(s4 + 1, 1, 8);
      STEP(s4 + 2, 2, 8);
      STEP(s4 + 3, 3, 8);
    }
    STEP(124, 0, 8);
    STEP(125, 1, 8);
    STEP(126, 2, 4);
    STEP(127, 3, 0);

#undef STEP
#undef GENW
#undef ISSUE
  } else {
    // fallback: single-buffer, f32->bf16 staging, 2 __syncthreads per step, k=0..8
    #pragma unroll 1
    for (int s = 0; s < 144; ++s) {
      const int r = s % 9, st = s / 9;
      const int d0 = kbase + st * 32;
      __syncthreads();
      { const int dd = tid & 31, cg = tid >> 5;
        const float* ws_ = w + (size_t)r * 1048576 + (size_t)(d0 + dd) * 1024 + colbase + cg * 4;
        #pragma unroll
        for (int p_ = 0; p_ < 8; ++p_) {
          f32x4 f_ = *(const f32x4*)(ws_ + p_ * 32);
          #pragma unroll
          for (int jj = 0; jj < 4; ++jj) {
            int col = cg * 4 + p_ * 32 + jj;
            int byt = col * 64 + ((dd & 7) << 1) + ((((dd >> 3) ^ swz_e(col)) & 3) << 4);
            *(unsigned short*)((char*)&Bsm[0][0] + byt) = f2bf(f_[jj]);
          } } }
      union { unsigned short u[8]; s16x8 v; } o0, o1;
      if (r == 0) {
        #pragma unroll
        for (int q = 0; q < 4; ++q) xq[q] = *(const f32x4*)(xrow + st * 32 + q * 4);
        #pragma unroll
        for (int i = 0; i < 16; ++i) { p1[i] = xq[i >> 2][i & 3]; p2[i] = 1.f; }
        #pragma unroll
        for (int i = 0; i < 8; ++i) {
          union { unsigned u; _Float16 f[2]; } t;
          t.f[0] = (_Float16)(p1[2 * i] + p1[2 * i]);
          t.f[1] = (_Float16)(p1[2 * i + 1] + p1[2 * i + 1]);
          x2h[i] = t.u;
          o0.u[i] = 0x3f80; o1.u[i] = 0x3f80;   // T_0 = 1
        }
      } else if (r == 1) {
        #pragma unroll
        for (int i = 0; i < 8; ++i) { o0.u[i] = f2bf(p1[i]); o1.u[i] = f2bf(p1[i + 8]); }
      } else {
        #pragma unroll
        for (int i = 0; i < 16; ++i) {
          union { unsigned u; _Float16 f[2]; } t; t.u = x2h[i >> 1];
          float cur = fmaf((float)t.f[i & 1], p1[i], -p2[i]);
          p2[i] = p1[i]; p1[i] = cur;
          if (i < 8) o0.u[i] = f2bf(cur); else o1.u[i - 8] = f2bf(cur);
        }
      }
      *(s16x8*)((char*)&Asm[0][0] + aw0) = o0.v;
      *(s16x8*)((char*)&Asm[0][0] + aw1) = o1.v;
      __syncthreads();
      s16x8 af[4];
      #pragma unroll
      for (int m = 0; m < 4; ++m)
        af[m] = *(const s16x8*)((char*)&Asm[0][0] + abase + m * 1024);
      #pragma unroll
      for (int n = 0; n < 8; ++n) {
        s16x8 bfr = *(const s16x8*)((char*)&Bsm[0][0] + bbase + n * 1024);
        #pragma unroll
        for (int m = 0; m < 4; ++m)
          acc[m][n] = __builtin_amdgcn_mfma_f32_16x16x32_bf16(af[m], bfr, acc[m][n], 0, 0, 0);
      }
    }
  }

  // epilogue: out += acc (split-K partial), hardware f32 atomics
  #pragma unroll
  for (int m = 0; m < 4; ++m) {
    const int r0 = rowbase + wr * 64 + m * 16 + lg * 4;
    #pragma unroll
    for (int n = 0; n < 8; ++n) {
      const int c = colbase + wc * 128 + n * 16 + la;
      #pragma unroll
      for (int j = 0; j < 4; ++j)
        unsafeAtomicAdd(&out[(size_t)(r0 + j) * 1024 + c], acc[m][n][j]);
    }
  }
}

extern "C" void kernel_launch(void* const* d_in, const int* in_sizes, int n_in,
                              void* d_out, int out_size, void* d_ws, size_t ws_size,
                              hipStream_t stream) {
  const float* x = (const float*)d_in[0];
  const float* w = (const float*)d_in[1];
  float* out = (float*)d_out;

  const size_t WT_BYTES = (size_t)8 * 1024 * 1024 * 2;   // 16 MiB
  const bool use_ws = ws_size >= WT_BYTES + 4096;

  if (use_ws) {
    short* wt   = (short*)d_ws;
    float* bias = (float*)((char*)d_ws + WT_BYTES);
    transpose_w<<<2048, 256, 0, stream>>>(w, wt);
    bias_k<<<16, 256, 0, stream>>>(w, bias);
    init_out<<<8192, 256, 0, stream>>>(bias, out, 1);
    cheb_gemm<true><<<512, 256, 0, stream>>>(x, w, wt, out);
  } else {
    init_out<<<8192, 256, 0, stream>>>(nullptr, out, 0);
    cheb_gemm<false><<<512, 256, 0, stream>>>(x, w, nullptr, out);
  }
}

// Round 5
// 259.004 us; speedup vs baseline: 3.9489x; 1.5497x over previous
//
#include <hip/hip_runtime.h>
#include <hip/hip_bf16.h>
#include <stdint.h>

typedef float  f32x4 __attribute__((ext_vector_type(4)));
typedef short  s16x8 __attribute__((ext_vector_type(8)));

#define GLOAD_LDS16(g, l)                                                          \
  __builtin_amdgcn_global_load_lds(                                               \
      (const __attribute__((address_space(1))) unsigned int*)(g),                 \
      (__attribute__((address_space(3))) unsigned int*)(l), 16, 0, 0)

static __device__ __forceinline__ unsigned short f2bf(float f) {
  union { __hip_bfloat16 b; unsigned short s; } cv;
  cv.b = __float2bfloat16(f);          // RNE; compiler pairs into v_cvt_pk_bf16_f32
  return cv.s;
}

static __device__ __forceinline__ int swz_e(int r) { return ((r & 3) ^ ((r >> 2) & 1)); }
static __device__ __forceinline__ int swz_byte(int r, int c) {
  return r * 64 + (((c ^ swz_e(r)) & 3) << 4);
}

// ---------------- pre-pass: Wt[k-1][col][d] = bf16(W[k][d][col]), k = 1..8 ----------------
__global__ __launch_bounds__(256) void transpose_w(const float* __restrict__ w,
                                                   short* __restrict__ wt) {
  __shared__ unsigned int lds[64 * 33];
  const int t = threadIdx.x;
  const int bid = blockIdx.x;
  const int kb = bid >> 8;            // 0..7  (k = kb+1)
  const int db = (bid >> 4) & 15;
  const int cb = bid & 15;
  const int d0 = db * 64, c0 = cb * 64;
  const float* src = w + (size_t)(kb + 1) * 1048576 + (size_t)d0 * 1024 + c0;
  #pragma unroll
  for (int p = 0; p < 4; ++p) {
    int dl = p * 16 + (t >> 4);
    int c4 = (t & 15) * 4;
    f32x4 f = *(const f32x4*)(src + (size_t)dl * 1024 + c4);
    unsigned lo = (unsigned)f2bf(f.x) | ((unsigned)f2bf(f.y) << 16);
    unsigned hi = (unsigned)f2bf(f.z) | ((unsigned)f2bf(f.w) << 16);
    lds[dl * 33 + (t & 15) * 2]     = lo;
    lds[dl * 33 + (t & 15) * 2 + 1] = hi;
  }
  __syncthreads();
  const int col = t >> 2;   // 0..63
  const int dc  = t & 3;    // 16-d chunk
  union { unsigned short u[8]; s16x8 v; } o0, o1;
  #pragma unroll
  for (int j = 0; j < 16; ++j) {
    int dl = dc * 16 + j;
    unsigned word = lds[dl * 33 + (col >> 1)];
    unsigned short e = (col & 1) ? (unsigned short)(word >> 16) : (unsigned short)(word & 0xffffu);
    if (j < 8) o0.u[j] = e; else o1.u[j - 8] = e;
  }
  short* dst = wt + ((size_t)(kb * 1024 + c0 + col) * 1024 + d0 + dc * 16);
  *(s16x8*)dst       = o0.v;
  *(s16x8*)(dst + 8) = o1.v;
}

// ---------------- bias[c] = sum_d W[0][d][c] ----------------
__global__ __launch_bounds__(256) void bias_k(const float* __restrict__ w,
                                              float* __restrict__ b) {
  __shared__ float red[256];
  const int t = threadIdx.x;
  const int col = blockIdx.x * 64 + (t & 63);
  const int seg = t >> 6;
  float s = 0.f;
  const float* p = w + (size_t)(seg * 256) * 1024 + col;
  for (int d = 0; d < 256; ++d) s += p[(size_t)d * 1024];
  red[t] = s;
  __syncthreads();
  if (t < 64) b[col] = red[t] + red[t + 64] + red[t + 128] + red[t + 192];
}

// ---------------- out init: out[r][c] = bias[c] (or 0) ----------------
__global__ __launch_bounds__(256) void init_out(const float* __restrict__ bias,
                                                float* __restrict__ out, int has_bias) {
  const size_t i = (size_t)blockIdx.x * 256 + threadIdx.x;
  const int c = (int)((i * 4) & 1023);
  f32x4 v = has_bias ? *(const f32x4*)(bias + c) : (f32x4){0.f, 0.f, 0.f, 0.f};
  *(f32x4*)(out + i * 4) = v;
}

// ---------------- fused Chebyshev GEMM ----------------
// Round-2 proven skeleton: block 128M x 256N, split-K x2, 4 waves (2x2),
// wave 64x128, BK=32, double-buffered A+B, ONE __syncthreads per step
// (full drain = self-synchronizing blocks -> L2 locality).
// Round-5 deltas: (1) XCD-pinned (nb,kb) per XCD -> B panel L2-resident,
// (2) no setprio, (3) x prefetched one strip ahead, compile-time k unroll.
template <bool USE_WS>
__global__ __launch_bounds__(256, 2) void cheb_gemm(
    const float* __restrict__ x, const float* __restrict__ w,
    const short* __restrict__ wt, float* __restrict__ out) {
  __shared__ short Asm[2][4096];   // [buf][128 rows][32 dims] swizzled (16 KB)
  __shared__ short Bsm[2][8192];   // [buf][256 cols][32 dims] swizzled (32 KB)

  const int tid = threadIdx.x, lane = tid & 63, wid = tid >> 6;
  // XCD-pinned mapping: consecutive blockIdx round-robin XCDs -> bid&7 = XCD.
  // Each XCD owns ONE (nb,kb): B working set/XCD = 2 MiB, L2-resident.
  const int bid = blockIdx.x;
  const int xcd = bid & 7;
  const int mb  = bid >> 3;            // 0..63
  const int nb  = xcd >> 1, kb = xcd & 1;
  const int rowbase = mb * 128, colbase = nb * 256;
  const int kbase = kb * 512;
  const int wr = wid >> 1, wc = wid & 1;
  const int la = lane & 15, lg = lane >> 4;

  f32x4 acc[4][8];
  #pragma unroll
  for (int m = 0; m < 4; ++m)
    #pragma unroll
    for (int n = 0; n < 8; ++n) acc[m][n] = (f32x4){0.f, 0.f, 0.f, 0.f};

  // fragment read bases (swz_e(row+8j)==swz_e(row); strides multiple of 16)
  const int e_la = (la & 3) ^ ((la >> 2) & 1);
  const int abase = (wr * 64 + la) * 64 + ((lg ^ e_la) << 4);
  const int bbase = (wc * 128 + la) * 64 + ((lg ^ e_la) << 4);

  // A generation: thread owns row (tid&127), dims h*16 .. h*16+16 of each strip
  const int arow = tid & 127, h = tid >> 7;
  const int aw0 = swz_byte(arow, 2 * h), aw1 = swz_byte(arow, 2 * h + 1);
  const float* xrow = x + (size_t)(rowbase + arow) * 1024 + kbase + h * 16;

  // B gload: per-lane pre-swizzled source (round-2 proven)
  int bcol[4], bgoff[4];
  #pragma unroll
  for (int j = 0; j < 4; ++j) {
    bcol[j]  = (wid * 4 + j) * 16 + (lane >> 2);
    bgoff[j] = ((lane & 3) ^ swz_e(bcol[j])) * 8;
  }

  float p1[16], p2[16];
  unsigned x2h[8];     // 2x packed f16x2 (numerics validated rounds 3-4)
  f32x4 xq[4];         // next-strip x prefetch (16 VGPRs)

#define ISSUE(K_, ST_, BUF)                                                        \
  { _Pragma("unroll")                                                              \
    for (int j_ = 0; j_ < 4; ++j_) {                                               \
      const short* g_ = wt + ((size_t)(K_) << 20) +                                \
          (size_t)(colbase + bcol[j_]) * 1024 + kbase + (ST_) * 32 + bgoff[j_];    \
      GLOAD_LDS16(g_, (char*)&Bsm[BUF][0] + (wid * 4 + j_) * 1024);                \
    } }

#define STAGE_B_F32(K_, ST_, BUF)                                                  \
  { const int d0_ = kbase + (ST_) * 32;                                            \
    const int dd_ = tid & 31, cg_ = tid >> 5;                                      \
    const float* ws_ = w + (size_t)(K_) * 1048576 + (size_t)(d0_ + dd_) * 1024 + colbase + cg_ * 4; \
    _Pragma("unroll")                                                              \
    for (int p_ = 0; p_ < 8; ++p_) {                                               \
      f32x4 f_ = *(const f32x4*)(ws_ + p_ * 32);                                   \
      _Pragma("unroll")                                                            \
      for (int jj_ = 0; jj_ < 4; ++jj_) {                                          \
        int col_ = cg_ * 4 + p_ * 32 + jj_;                                        \
        int byt_ = col_ * 64 + ((dd_ & 7) << 1) + ((((dd_ >> 3) ^ swz_e(col_)) & 3) << 4); \
        *(unsigned short*)((char*)&Bsm[BUF][0] + byt_) = f2bf(f_[jj_]);            \
      } } }

// GENW: compute A sub-tile for recurrence index R_ (0 => T_1 = x, consumes xq,
// then prefetches strip SNEXT_), write bf16 to Asm[BUF_].
#define GENW(R_, SNEXT_, BUF_)                                                     \
  { union { unsigned short u[8]; s16x8 v; } o0_, o1_;                              \
    if ((R_) == 0) {                                                               \
      _Pragma("unroll")                                                            \
      for (int i_ = 0; i_ < 16; ++i_) { p1[i_] = xq[i_ >> 2][i_ & 3]; p2[i_] = 1.f; } \
      _Pragma("unroll")                                                            \
      for (int i_ = 0; i_ < 8; ++i_) {                                             \
        union { unsigned u; _Float16 f[2]; } t_;                                   \
        t_.f[0] = (_Float16)(p1[2 * i_]     + p1[2 * i_]);                         \
        t_.f[1] = (_Float16)(p1[2 * i_ + 1] + p1[2 * i_ + 1]);                     \
        x2h[i_] = t_.u; }                                                          \
      if ((SNEXT_) < 16) {                                                         \
        _Pragma("unroll")                                                          \
        for (int q_ = 0; q_ < 4; ++q_)                                             \
          xq[q_] = *(const f32x4*)(xrow + (SNEXT_) * 32 + q_ * 4); }               \
      _Pragma("unroll")                                                            \
      for (int i_ = 0; i_ < 8; ++i_) { o0_.u[i_] = f2bf(p1[i_]); o1_.u[i_] = f2bf(p1[i_ + 8]); } \
    } else {                                                                       \
      _Pragma("unroll")                                                            \
      for (int i_ = 0; i_ < 16; ++i_) {                                            \
        union { unsigned u; _Float16 f[2]; } t_; t_.u = x2h[i_ >> 1];              \
        float cur_ = fmaf((float)t_.f[i_ & 1], p1[i_], -p2[i_]);                   \
        p2[i_] = p1[i_]; p1[i_] = cur_;                                            \
        unsigned short e_ = f2bf(cur_);                                            \
        if (i_ < 8) o0_.u[i_] = e_; else o1_.u[i_ - 8] = e_; } }                   \
    *(s16x8*)((char*)&Asm[BUF_][0] + aw0) = o0_.v;                                 \
    *(s16x8*)((char*)&Asm[BUF_][0] + aw1) = o1_.v; }

  if constexpr (USE_WS) {
    // prologue: x strip 0, B tile (k=0, strip 0) into buf 0, A(T_1,strip0) into buf 0
    #pragma unroll
    for (int q = 0; q < 4; ++q) xq[q] = *(const f32x4*)(xrow + q * 4);
    ISSUE(0, 0, 0);
    GENW(0, 1, 0);
    __syncthreads();

    #pragma unroll 1
    for (int s = 0; s < 16; ++s) {
      #pragma unroll
      for (int kk = 0; kk < 8; ++kk) {       // kk compile-time after unroll
        const int cur = kk & 1;
        if (!(s == 15 && kk == 7)) {
          const int knext = (kk + 1) & 7;
          const int snext = (kk == 7) ? (s + 1) : s;
          ISSUE(knext, snext, cur ^ 1);
          GENW(knext, (kk == 7) ? (s + 2) : (s + 1), cur ^ 1);
        }
        s16x8 af_[4];
        #pragma unroll
        for (int m = 0; m < 4; ++m)
          af_[m] = *(const s16x8*)((char*)&Asm[cur][0] + abase + m * 1024);
        #pragma unroll
        for (int n = 0; n < 8; ++n) {
          s16x8 bf_ = *(const s16x8*)((char*)&Bsm[cur][0] + bbase + n * 1024);
          #pragma unroll
          for (int m = 0; m < 4; ++m)
            acc[m][n] = __builtin_amdgcn_mfma_f32_16x16x32_bf16(af_[m], bf_, acc[m][n], 0, 0, 0);
        }
        __syncthreads();
      }
    }
  } else {
    // fallback (no workspace): single-buffer, f32->bf16 staging, k=0..8
    #pragma unroll 1
    for (int s = 0; s < 144; ++s) {
      const int r = s % 9, st = s / 9;
      __syncthreads();
      STAGE_B_F32(r, st, 0);
      union { unsigned short u[8]; s16x8 v; } o0, o1;
      if (r == 0) {
        #pragma unroll
        for (int q = 0; q < 4; ++q) xq[q] = *(const f32x4*)(xrow + st * 32 + q * 4);
        #pragma unroll
        for (int i = 0; i < 16; ++i) { p1[i] = xq[i >> 2][i & 3]; p2[i] = 1.f; }
        #pragma unroll
        for (int i = 0; i < 8; ++i) {
          union { unsigned u; _Float16 f[2]; } t;
          t.f[0] = (_Float16)(p1[2 * i] + p1[2 * i]);
          t.f[1] = (_Float16)(p1[2 * i + 1] + p1[2 * i + 1]);
          x2h[i] = t.u;
          o0.u[i] = 0x3f80; o1.u[i] = 0x3f80;   // T_0 = 1
        }
      } else if (r == 1) {
        #pragma unroll
        for (int i = 0; i < 8; ++i) { o0.u[i] = f2bf(p1[i]); o1.u[i] = f2bf(p1[i + 8]); }
      } else {
        #pragma unroll
        for (int i = 0; i < 16; ++i) {
          union { unsigned u; _Float16 f[2]; } t; t.u = x2h[i >> 1];
          float cur = fmaf((float)t.f[i & 1], p1[i], -p2[i]);
          p2[i] = p1[i]; p1[i] = cur;
          if (i < 8) o0.u[i] = f2bf(cur); else o1.u[i - 8] = f2bf(cur);
        }
      }
      *(s16x8*)((char*)&Asm[0][0] + aw0) = o0.v;
      *(s16x8*)((char*)&Asm[0][0] + aw1) = o1.v;
      __syncthreads();
      s16x8 af[4];
      #pragma unroll
      for (int m = 0; m < 4; ++m)
        af[m] = *(const s16x8*)((char*)&Asm[0][0] + abase + m * 1024);
      #pragma unroll
      for (int n = 0; n < 8; ++n) {
        s16x8 bfr = *(const s16x8*)((char*)&Bsm[0][0] + bbase + n * 1024);
        #pragma unroll
        for (int m = 0; m < 4; ++m)
          acc[m][n] = __builtin_amdgcn_mfma_f32_16x16x32_bf16(af[m], bfr, acc[m][n], 0, 0, 0);
      }
    }
  }

#undef GENW
#undef ISSUE
#undef STAGE_B_F32

  // epilogue: out += acc (split-K partial), hardware f32 atomics
  #pragma unroll
  for (int m = 0; m < 4; ++m) {
    const int r0 = rowbase + wr * 64 + m * 16 + lg * 4;
    #pragma unroll
    for (int n = 0; n < 8; ++n) {
      const int c = colbase + wc * 128 + n * 16 + la;
      #pragma unroll
      for (int j = 0; j < 4; ++j)
        unsafeAtomicAdd(&out[(size_t)(r0 + j) * 1024 + c], acc[m][n][j]);
    }
  }
}

extern "C" void kernel_launch(void* const* d_in, const int* in_sizes, int n_in,
                              void* d_out, int out_size, void* d_ws, size_t ws_size,
                              hipStream_t stream) {
  const float* x = (const float*)d_in[0];
  const float* w = (const float*)d_in[1];
  float* out = (float*)d_out;

  const size_t WT_BYTES = (size_t)8 * 1024 * 1024 * 2;   // 16 MiB
  const bool use_ws = ws_size >= WT_BYTES + 4096;

  if (use_ws) {
    short* wt   = (short*)d_ws;
    float* bias = (float*)((char*)d_ws + WT_BYTES);
    transpose_w<<<2048, 256, 0, stream>>>(w, wt);
    bias_k<<<16, 256, 0, stream>>>(w, bias);
    init_out<<<8192, 256, 0, stream>>>(bias, out, 1);
    cheb_gemm<true><<<512, 256, 0, stream>>>(x, w, wt, out);
  } else {
    init_out<<<8192, 256, 0, stream>>>(nullptr, out, 0);
    cheb_gemm<false><<<512, 256, 0, stream>>>(x, w, nullptr, out);
  }
}

// Round 6
// 214.149 us; speedup vs baseline: 4.7761x; 1.2095x over previous
//
#include <hip/hip_runtime.h>
#include <hip/hip_bf16.h>
#include <stdint.h>

typedef float  f32x4 __attribute__((ext_vector_type(4)));
typedef short  s16x8 __attribute__((ext_vector_type(8)));

#define GLOAD_LDS16(g, l)                                                          \
  __builtin_amdgcn_global_load_lds(                                               \
      (const __attribute__((address_space(1))) unsigned int*)(g),                 \
      (__attribute__((address_space(3))) unsigned int*)(l), 16, 0, 0)

#define WAITVM_(N) asm volatile("s_waitcnt vmcnt(" #N ")" ::: "memory")
#define WAITVM(N) WAITVM_(N)
#define WAITLGKM0 asm volatile("s_waitcnt lgkmcnt(0)" ::: "memory")

static __device__ __forceinline__ unsigned short f2bf(float f) {
  union { __hip_bfloat16 b; unsigned short s; } cv;
  cv.b = __float2bfloat16(f);          // RNE; compiler pairs into v_cvt_pk_bf16_f32
  return cv.s;
}

static __device__ __forceinline__ int swz_e(int r) { return ((r & 3) ^ ((r >> 2) & 1)); }
static __device__ __forceinline__ int swz_byte(int r, int c) {
  return r * 64 + (((c ^ swz_e(r)) & 3) << 4);
}

// ---------------- pre-pass: Wt[k-1][col][d] = bf16(W[k][d][col]), k = 1..8 ----------------
__global__ __launch_bounds__(256) void transpose_w(const float* __restrict__ w,
                                                   short* __restrict__ wt) {
  __shared__ unsigned int lds[64 * 33];
  const int t = threadIdx.x;
  const int bid = blockIdx.x;
  const int kb = bid >> 8;            // 0..7  (k = kb+1)
  const int db = (bid >> 4) & 15;
  const int cb = bid & 15;
  const int d0 = db * 64, c0 = cb * 64;
  const float* src = w + (size_t)(kb + 1) * 1048576 + (size_t)d0 * 1024 + c0;
  #pragma unroll
  for (int p = 0; p < 4; ++p) {
    int dl = p * 16 + (t >> 4);
    int c4 = (t & 15) * 4;
    f32x4 f = *(const f32x4*)(src + (size_t)dl * 1024 + c4);
    unsigned lo = (unsigned)f2bf(f.x) | ((unsigned)f2bf(f.y) << 16);
    unsigned hi = (unsigned)f2bf(f.z) | ((unsigned)f2bf(f.w) << 16);
    lds[dl * 33 + (t & 15) * 2]     = lo;
    lds[dl * 33 + (t & 15) * 2 + 1] = hi;
  }
  __syncthreads();
  const int col = t >> 2;   // 0..63
  const int dc  = t & 3;    // 16-d chunk
  union { unsigned short u[8]; s16x8 v; } o0, o1;
  #pragma unroll
  for (int j = 0; j < 16; ++j) {
    int dl = dc * 16 + j;
    unsigned word = lds[dl * 33 + (col >> 1)];
    unsigned short e = (col & 1) ? (unsigned short)(word >> 16) : (unsigned short)(word & 0xffffu);
    if (j < 8) o0.u[j] = e; else o1.u[j - 8] = e;
  }
  short* dst = wt + ((size_t)(kb * 1024 + c0 + col) * 1024 + d0 + dc * 16);
  *(s16x8*)dst       = o0.v;
  *(s16x8*)(dst + 8) = o1.v;
}

// ---------------- bias[c] = sum_d W[0][d][c] ----------------
__global__ __launch_bounds__(256) void bias_k(const float* __restrict__ w,
                                              float* __restrict__ b) {
  __shared__ float red[256];
  const int t = threadIdx.x;
  const int col = blockIdx.x * 64 + (t & 63);
  const int seg = t >> 6;
  float s = 0.f;
  const float* p = w + (size_t)(seg * 256) * 1024 + col;
  for (int d = 0; d < 256; ++d) s += p[(size_t)d * 1024];
  red[t] = s;
  __syncthreads();
  if (t < 64) b[col] = red[t] + red[t + 64] + red[t + 128] + red[t + 192];
}

// ---------------- out init: out[r][c] = bias[c] (or 0) ----------------
__global__ __launch_bounds__(256) void init_out(const float* __restrict__ bias,
                                                float* __restrict__ out, int has_bias) {
  const size_t i = (size_t)blockIdx.x * 256 + threadIdx.x;
  const int c = (int)((i * 4) & 1023);
  f32x4 v = has_bias ? *(const f32x4*)(bias + c) : (f32x4){0.f, 0.f, 0.f, 0.f};
  *(f32x4*)(out + i * 4) = v;
}

// ---------------- fused Chebyshev GEMM ----------------
// R2 skeleton (block 128M x 256N, split-K x2, 4 waves 64x128, BK=32, dbuf A).
// Round-6 deltas: (1) counted vmcnt(4) + raw s_barrier (no per-step DMA drain),
// 3-buffer B, 2-deep prefetch; (2) XCD-pinned (nb,kb) -> B panel 2 MiB, L2-resident
// under drift; (3) x prefetched 5 steps ahead; (4) compact runtime-t loop body.
template <bool USE_WS>
__global__ __launch_bounds__(256, 2) void cheb_gemm(
    const float* __restrict__ x, const float* __restrict__ w,
    const short* __restrict__ wt, float* __restrict__ out) {
  __shared__ short Asm[2][4096];   // 2 x 8KB  [128 rows][32 dims] swizzled
  __shared__ short Bsm[3][8192];   // 3 x 16KB [256 cols][32 dims] swizzled

  const int tid = threadIdx.x, lane = tid & 63, wid = tid >> 6;
  // XCD-pinned mapping: bid&7 = XCD (hw round-robin). One (nb,kb) per XCD.
  const int bid = blockIdx.x;
  const int xcd = bid & 7;
  const int mb  = bid >> 3;            // 0..63
  const int nb  = xcd >> 1, kb = xcd & 1;
  const int rowbase = mb * 128, colbase = nb * 256;
  const int kbase = kb * 512;
  const int wr = wid >> 1, wc = wid & 1;
  const int la = lane & 15, lg = lane >> 4;

  f32x4 acc[4][8];
  #pragma unroll
  for (int m = 0; m < 4; ++m)
    #pragma unroll
    for (int n = 0; n < 8; ++n) acc[m][n] = (f32x4){0.f, 0.f, 0.f, 0.f};

  // fragment read bases (swz_e(row)==swz_e(la): strides are multiples of 16)
  const int e_la = (la & 3) ^ ((la >> 2) & 1);
  const int abase = (wr * 64 + la) * 64 + ((lg ^ e_la) << 4);
  const int bbase = (wc * 128 + la) * 64 + ((lg ^ e_la) << 4);

  // A generation: thread owns row (tid&127), dims h*16 .. +16 of each strip
  const int arow = tid & 127, h = tid >> 7;
  const int aw0 = swz_byte(arow, 2 * h), aw1 = swz_byte(arow, 2 * h + 1);
  const float* xrow = x + (size_t)(rowbase + arow) * 1024 + kbase + h * 16;

  float p1[16], p2[16];
  unsigned x2h[8];     // 2x packed f16x2 (numerics validated rounds 3-5)
  f32x4 xq[4];         // x for the NEXT strip (prefetched 5+ steps early)

  if constexpr (USE_WS) {
    // per-lane pre-swizzled gload source; tile j-offset = j*16384 shorts
    const int bcol0  = wid * 64 + (lane >> 2);
    const int goff   = ((lane & 3) ^ swz_e(lane >> 2)) * 8;
    const short* gptr = wt + (size_t)(colbase + bcol0) * 1024 + kbase + goff; // tile 0

#define ISSUE_AT(PTR, WOFF)                                                        \
    { _Pragma("unroll")                                                            \
      for (int j_ = 0; j_ < 4; ++j_)                                               \
        GLOAD_LDS16((PTR) + j_ * 16384,                                            \
                    (char*)&Bsm[0][0] + (WOFF) + (wid * 4 + j_) * 1024); }

    // ---- prologue ----
    #pragma unroll
    for (int q = 0; q < 4; ++q) xq[q] = *(const f32x4*)(xrow + q * 4);  // strip 0
    ISSUE_AT(gptr, 0);          gptr += 1048576;   // tile 0 -> buf 0
    ISSUE_AT(gptr, 16384);      gptr += 1048576;   // tile 1 -> buf 1 ; gptr at tile 2
    // GEN(0): T_1 = x (consumes xq strip 0) -> Asm[0]
    {
      union { unsigned short u[8]; s16x8 v; } o0, o1;
      #pragma unroll
      for (int i = 0; i < 16; ++i) { p1[i] = xq[i >> 2][i & 3]; p2[i] = 1.f; }
      #pragma unroll
      for (int i = 0; i < 8; ++i) {
        union { unsigned u; _Float16 f[2]; } t2;
        t2.f[0] = (_Float16)(p1[2 * i] + p1[2 * i]);
        t2.f[1] = (_Float16)(p1[2 * i + 1] + p1[2 * i + 1]);
        x2h[i] = t2.u;
        o0.u[i] = f2bf(p1[i]); o1.u[i] = f2bf(p1[i + 8]);
      }
      *(s16x8*)((char*)&Asm[0][0] + aw0) = o0.v;
      *(s16x8*)((char*)&Asm[0][0] + aw1) = o1.v;
    }
    WAITLGKM0;
    WAITVM(4);                       // tile 0 landed (tile 1 still in flight)
    __builtin_amdgcn_sched_barrier(0);
    __builtin_amdgcn_s_barrier();
    __builtin_amdgcn_sched_barrier(0);

    int wroff = 32768;               // LDS byte offset of buf for tile t+2 (t=0 -> buf 2)
    int rdoff = 0;                   // buf for tile t
    int ard   = 0;                   // Asm byte offset for step t

    #pragma unroll 1
    for (int t = 0; t < 128; ++t) {
      // x prefetch for strip (t>>3)+1, 5 steps before its r==0 consumption
      if ((t & 7) == 2 && t < 120) {
        const float* xs = xrow + ((t >> 3) + 1) * 32;
        #pragma unroll
        for (int q = 0; q < 4; ++q) xq[q] = *(const f32x4*)(xs + q * 4);
      }
      // B prefetch, depth 2 (tile t+2)
      if (t + 2 < 128) {
        ISSUE_AT(gptr, wroff);
        gptr += ((t & 7) == 5) ? (32 - 7 * 1048576) : 1048576;
        wroff = (wroff == 32768) ? 0 : wroff + 16384;
      }
      // A for step t+1 -> Asm[(t+1)&1]
      if (t + 1 < 128) {
        const int rn = (t + 1) & 7;
        union { unsigned short u[8]; s16x8 v; } o0, o1;
        if (rn == 0) {
          #pragma unroll
          for (int i = 0; i < 16; ++i) { p1[i] = xq[i >> 2][i & 3]; p2[i] = 1.f; }
          #pragma unroll
          for (int i = 0; i < 8; ++i) {
            union { unsigned u; _Float16 f[2]; } t2;
            t2.f[0] = (_Float16)(p1[2 * i] + p1[2 * i]);
            t2.f[1] = (_Float16)(p1[2 * i + 1] + p1[2 * i + 1]);
            x2h[i] = t2.u;
            o0.u[i] = f2bf(p1[i]); o1.u[i] = f2bf(p1[i + 8]);
          }
        } else {
          #pragma unroll
          for (int i = 0; i < 16; ++i) {
            union { unsigned u; _Float16 f[2]; } t2; t2.u = x2h[i >> 1];
            float cur = fmaf((float)t2.f[i & 1], p1[i], -p2[i]);
            p2[i] = p1[i]; p1[i] = cur;
            unsigned short e = f2bf(cur);
            if (i < 8) o0.u[i] = e; else o1.u[i - 8] = e;
          }
        }
        *(s16x8*)((char*)&Asm[0][0] + (ard ^ 8192) + aw0) = o0.v;
        *(s16x8*)((char*)&Asm[0][0] + (ard ^ 8192) + aw1) = o1.v;
      }
      // MFMA on (Asm[t&1], Bsm[t%3])
      s16x8 af[4];
      #pragma unroll
      for (int m = 0; m < 4; ++m)
        af[m] = *(const s16x8*)((char*)&Asm[0][0] + ard + abase + m * 1024);
      __builtin_amdgcn_s_setprio(1);
      #pragma unroll
      for (int n = 0; n < 8; ++n) {
        s16x8 bfr = *(const s16x8*)((char*)&Bsm[0][0] + rdoff + bbase + n * 1024);
        #pragma unroll
        for (int m = 0; m < 4; ++m)
          acc[m][n] = __builtin_amdgcn_mfma_f32_16x16x32_bf16(af[m], bfr, acc[m][n], 0, 0, 0);
      }
      __builtin_amdgcn_s_setprio(0);
      // end-of-step: A writes visible; tile t+1 landed; NO full drain
      WAITLGKM0;
      if (t < 126) { WAITVM(4); } else { WAITVM(0); }
      __builtin_amdgcn_sched_barrier(0);
      __builtin_amdgcn_s_barrier();
      __builtin_amdgcn_sched_barrier(0);
      rdoff = (rdoff == 32768) ? 0 : rdoff + 16384;
      ard ^= 8192;
    }
#undef ISSUE_AT
  } else {
    // fallback (no workspace): single-buffer, f32->bf16 staging, k=0..8
    #pragma unroll 1
    for (int s = 0; s < 144; ++s) {
      const int r = s % 9, st = s / 9;
      const int d0 = kbase + st * 32;
      __syncthreads();
      { const int dd = tid & 31, cg = tid >> 5;
        const float* ws_ = w + (size_t)r * 1048576 + (size_t)(d0 + dd) * 1024 + colbase + cg * 4;
        #pragma unroll
        for (int p_ = 0; p_ < 8; ++p_) {
          f32x4 f_ = *(const f32x4*)(ws_ + p_ * 32);
          #pragma unroll
          for (int jj = 0; jj < 4; ++jj) {
            int col = cg * 4 + p_ * 32 + jj;
            int byt = col * 64 + ((dd & 7) << 1) + ((((dd >> 3) ^ swz_e(col)) & 3) << 4);
            *(unsigned short*)((char*)&Bsm[0][0] + byt) = f2bf(f_[jj]);
          } } }
      union { unsigned short u[8]; s16x8 v; } o0, o1;
      if (r == 0) {
        #pragma unroll
        for (int q = 0; q < 4; ++q) xq[q] = *(const f32x4*)(xrow + st * 32 + q * 4);
        #pragma unroll
        for (int i = 0; i < 16; ++i) { p1[i] = xq[i >> 2][i & 3]; p2[i] = 1.f; }
        #pragma unroll
        for (int i = 0; i < 8; ++i) {
          union { unsigned u; _Float16 f[2]; } t2;
          t2.f[0] = (_Float16)(p1[2 * i] + p1[2 * i]);
          t2.f[1] = (_Float16)(p1[2 * i + 1] + p1[2 * i + 1]);
          x2h[i] = t2.u;
          o0.u[i] = 0x3f80; o1.u[i] = 0x3f80;   // T_0 = 1
        }
      } else if (r == 1) {
        #pragma unroll
        for (int i = 0; i < 8; ++i) { o0.u[i] = f2bf(p1[i]); o1.u[i] = f2bf(p1[i + 8]); }
      } else {
        #pragma unroll
        for (int i = 0; i < 16; ++i) {
          union { unsigned u; _Float16 f[2]; } t2; t2.u = x2h[i >> 1];
          float cur = fmaf((float)t2.f[i & 1], p1[i], -p2[i]);
          p2[i] = p1[i]; p1[i] = cur;
          if (i < 8) o0.u[i] = f2bf(cur); else o1.u[i - 8] = f2bf(cur);
        }
      }
      *(s16x8*)((char*)&Asm[0][0] + aw0) = o0.v;
      *(s16x8*)((char*)&Asm[0][0] + aw1) = o1.v;
      __syncthreads();
      s16x8 af[4];
      #pragma unroll
      for (int m = 0; m < 4; ++m)
        af[m] = *(const s16x8*)((char*)&Asm[0][0] + abase + m * 1024);
      #pragma unroll
      for (int n = 0; n < 8; ++n) {
        s16x8 bfr = *(const s16x8*)((char*)&Bsm[0][0] + bbase + n * 1024);
        #pragma unroll
        for (int m = 0; m < 4; ++m)
          acc[m][n] = __builtin_amdgcn_mfma_f32_16x16x32_bf16(af[m], bfr, acc[m][n], 0, 0, 0);
      }
    }
  }

  // epilogue: out += acc (split-K partial), hardware f32 atomics
  #pragma unroll
  for (int m = 0; m < 4; ++m) {
    const int r0 = rowbase + wr * 64 + m * 16 + lg * 4;
    #pragma unroll
    for (int n = 0; n < 8; ++n) {
      const int c = colbase + wc * 128 + n * 16 + la;
      #pragma unroll
      for (int j = 0; j < 4; ++j)
        unsafeAtomicAdd(&out[(size_t)(r0 + j) * 1024 + c], acc[m][n][j]);
    }
  }
}

extern "C" void kernel_launch(void* const* d_in, const int* in_sizes, int n_in,
                              void* d_out, int out_size, void* d_ws, size_t ws_size,
                              hipStream_t stream) {
  const float* x = (const float*)d_in[0];
  const float* w = (const float*)d_in[1];
  float* out = (float*)d_out;

  const size_t WT_BYTES = (size_t)8 * 1024 * 1024 * 2;   // 16 MiB
  const bool use_ws = ws_size >= WT_BYTES + 4096;

  if (use_ws) {
    short* wt   = (short*)d_ws;
    float* bias = (float*)((char*)d_ws + WT_BYTES);
    transpose_w<<<2048, 256, 0, stream>>>(w, wt);
    bias_k<<<16, 256, 0, stream>>>(w, bias);
    init_out<<<8192, 256, 0, stream>>>(bias, out, 1);
    cheb_gemm<true><<<512, 256, 0, stream>>>(x, w, wt, out);
  } else {
    init_out<<<8192, 256, 0, stream>>>(nullptr, out, 0);
    cheb_gemm<false><<<512, 256, 0, stream>>>(x, w, nullptr, out);
  }
}